// Round 11
// baseline (445.983 us; speedup 1.0000x reference)
//
#include <hip/hip_runtime.h>
#include <hip/hip_bf16.h>

// RFAConv, round 11: SPLIT kernels through d_ws (if big enough), else r5 fused fallback.
//  producer: phase-1 only, 4 blocks/CU (32 waves/CU), LDS-restaged coalesced v writes.
//  consumer: pure GEMM out = relu(bn2(W2 @ v^T + cb)), reg-staged LDS dbuf, 6x192k chunks.

#define CCH  128
#define OCN  256
#define HH   96
#define WWD  96
#define KCH  1152
#define PIMG 9216
#define BNP  64
#define NBLK 144
#define NT   512
// fused fallback
#define CC   32
#define KC   288
#define VP   296
// consumer GEMM
#define KCB  192      // k per chunk (6 chunks, 6 ksteps each)
#define VPB  200      // LDS pitch ushort (rows 16B-aligned: 400B)

using short8   = __attribute__((ext_vector_type(8))) short;
using f32x4    = __attribute__((ext_vector_type(4))) float;
using f32x2    = __attribute__((ext_vector_type(2))) float;
using ushort2v = __attribute__((ext_vector_type(2))) ushort;

__device__ __forceinline__ ushort bf16bits(float f) {
    __hip_bfloat16 h = __float2bfloat16(f);
    return *reinterpret_cast<ushort*>(&h);
}

struct NB { f32x2 p[4]; float s; };

// ---- prepass: W2->bf16, fold bn1 into dwconv weights, w1*(1/9)*log2e ----
__global__ void prep_kernel(const float* __restrict__ W2, const float* __restrict__ gfw,
                            const float* __restrict__ bn1g, const float* __restrict__ bn1b,
                            const float* __restrict__ bn1m, const float* __restrict__ bn1v,
                            const float* __restrict__ w1,
                            ushort* __restrict__ W2bf, float* __restrict__ gws,
                            float* __restrict__ shiftv, float* __restrict__ w1s) {
    int i = blockIdx.x * 256 + threadIdx.x;
    if (i < OCN * KCH) {
        W2bf[i] = bf16bits(W2[i]);
    } else if (i < OCN * KCH + KCH) {
        const int ch = i - OCN * KCH;
        const float sc = bn1g[ch] * rsqrtf(bn1v[ch] + 1e-5f);
        shiftv[ch] = bn1b[ch] - bn1m[ch] * sc;
        #pragma unroll
        for (int t = 0; t < 9; ++t) gws[ch * 12 + t] = gfw[ch * 9 + t] * sc;
    } else if (i < OCN * KCH + KCH + CCH) {
        const int c = i - OCN * KCH - KCH;
        #pragma unroll
        for (int n = 0; n < 9; ++n)
            w1s[c * 12 + n] = w1[c * 9 + n] * (1.f / 9.f) * 1.4426950408889634f;
    }
}

// =================== producer: v[pix][k] (bf16) ===================
__global__ __launch_bounds__(NT, 8) void rfa_prod_kernel(
    const float* __restrict__ x,
    const float* __restrict__ gws, const float* __restrict__ shiftv,
    const float* __restrict__ w1s,
    ushort* __restrict__ vout)          // [73728][1152]
{
    __shared__ ushort tile[BNP * VP];   // 37888 B -> 4 blocks/CU

    const int bid = blockIdx.x;
    const int wk  = (bid & 7) * NBLK + (bid >> 3);   // 1152 blocks, bijective
    const int b   = wk / NBLK;
    const int P0  = (wk % NBLK) * BNP;

    const int tid  = threadIdx.x;
    const int lane = tid & 63;
    const int wid  = __builtin_amdgcn_readfirstlane(tid >> 6);   // 0..7

    const int px = lane;
    const int p  = P0 + px;
    const int h  = p / WWD;
    const int w  = p - h * WWD;

    int off9[9];
    f32x2 okp[4];
    float ok8;
    {
        float okr[3], okc[3];
        int hro[3], wxc[3];
        #pragma unroll
        for (int d = 0; d < 3; ++d) {
            int hy = h + d - 1;
            okr[d] = ((unsigned)hy < (unsigned)HH) ? 1.f : 0.f;
            hro[d] = ((hy < 0) ? 0 : (hy > 95 ? 95 : hy)) * WWD;
            int wx = w + d - 1;
            okc[d] = ((unsigned)wx < (unsigned)WWD) ? 1.f : 0.f;
            wxc[d] = (wx < 0) ? 0 : (wx > 95 ? 95 : wx);
        }
        #pragma unroll
        for (int dy = 0; dy < 3; ++dy)
            #pragma unroll
            for (int dx = 0; dx < 3; ++dx) off9[dy*3+dx] = hro[dy] + wxc[dx];
        okp[0] = f32x2{okr[0]*okc[0], okr[0]*okc[1]};
        okp[1] = f32x2{okr[0]*okc[2], okr[1]*okc[0]};
        okp[2] = f32x2{okr[1]*okc[1], okr[1]*okc[2]};
        okp[3] = f32x2{okr[2]*okc[0], okr[2]*okc[1]};
        ok8    = okr[2]*okc[2];
    }

    const float* xb = x + (size_t)b * CCH * PIMG;
    auto chan = [&](int q) { return (q >> 2) * CC + wid * 4 + (q & 3); };
    auto load_nb = [&](int c) {
        const float* xc = xb + (size_t)c * PIMG;
        NB r;
        float v0 = xc[off9[0]], v1 = xc[off9[1]], v2 = xc[off9[2]];
        float v3 = xc[off9[3]], v4 = xc[off9[4]], v5 = xc[off9[5]];
        float v6 = xc[off9[6]], v7 = xc[off9[7]], v8 = xc[off9[8]];
        r.p[0] = f32x2{v0,v1}; r.p[1] = f32x2{v2,v3};
        r.p[2] = f32x2{v4,v5}; r.p[3] = f32x2{v6,v7};
        r.s = v8;
        return r;
    };

    auto produce_one = [&](const NB& nb, int c, int cl, bool evenp) {
        f32x2 e[4];
        #pragma unroll
        for (int i = 0; i < 4; ++i) e[i] = nb.p[i] * okp[i];
        const float e8 = nb.s * ok8;
        f32x2 ps2 = (e[0] + e[1]) + (e[2] + e[3]);
        const float psum = ps2[0] + ps2[1] + e8;

        float at[9], ss = 0.f;
        const float* w1r = w1s + c * 12;
        #pragma unroll
        for (int n = 0; n < 9; ++n) { at[n] = __builtin_exp2f(psum * w1r[n]); ss += at[n]; }
        const float rs = __builtin_amdgcn_rcpf(ss);

        ushort u[9];
        #pragma unroll
        for (int n = 0; n < 9; ++n) {
            const int ch = c * 9 + n;
            const f32x2* gp = reinterpret_cast<const f32x2*>(gws + ch * 12);
            f32x2 f2 = f32x2{shiftv[ch], 0.f};
            #pragma unroll
            for (int u4 = 0; u4 < 4; ++u4) f2 = __builtin_elementwise_fma(e[u4], gp[u4], f2);
            float f = f2[0] + f2[1];
            f = fmaf(e8, gws[ch * 12 + 8], f);
            f = fmaxf(f, 0.f) * (at[n] * rs);
            u[n] = bf16bits(f);
        }
        ushort* vp = tile + px * VP + cl * 9;
        if (evenp) {
            ushort2v* q2 = reinterpret_cast<ushort2v*>(vp);
            q2[0] = ushort2v{u[0], u[1]}; q2[1] = ushort2v{u[2], u[3]};
            q2[2] = ushort2v{u[4], u[5]}; q2[3] = ushort2v{u[6], u[7]};
            vp[8] = u[8];
        } else {
            vp[0] = u[0];
            ushort2v* q2 = reinterpret_cast<ushort2v*>(vp + 1);
            q2[0] = ushort2v{u[1], u[2]}; q2[1] = ushort2v{u[3], u[4]};
            q2[2] = ushort2v{u[5], u[6]}; q2[3] = ushort2v{u[7], u[8]};
        }
    };

    NB nb = load_nb(chan(0));
    for (int ck = 0; ck < 4; ++ck) {
        #pragma unroll
        for (int t = 0; t < 4; ++t) {
            const int q  = ck * 4 + t;
            const int qn = (q + 1 > 15) ? 15 : q + 1;
            NB nbn = load_nb(chan(qn));
            produce_one(nb, chan(q), wid * 4 + t, (t & 1) == 0);
            nb = nbn;
        }
        __syncthreads();   // tile(ck) complete

        // flush tile -> vout, coalesced dwords. 64 rows x 144 dwords.
        const uint* lw = reinterpret_cast<const uint*>(tile);
        uint* vd = reinterpret_cast<uint*>(vout);
        #pragma unroll
        for (int i = 0; i < 18; ++i) {
            const int flat = i * 512 + tid;
            const int row  = flat / 144;
            const int col  = flat - row * 144;
            vd[(size_t)(b * PIMG + P0 + row) * 576 + ck * 144 + col] = lw[row * 148 + col];
        }
        __syncthreads();   // tile free for next chunk
    }
}

// =================== consumer: out = relu(bn2(W2 @ v^T + cb)) ===================
__global__ __launch_bounds__(NT, 4) void rfa_gemm_kernel(
    const ushort* __restrict__ W2bf, const ushort* __restrict__ v,
    const float* __restrict__ cbias,
    const float* __restrict__ bn2g, const float* __restrict__ bn2b,
    const float* __restrict__ bn2m, const float* __restrict__ bn2v,
    float* __restrict__ out)
{
    __shared__ ushort vt[2][BNP * VPB];   // 2 x 25600 B = 51200 B

    const int bid = blockIdx.x;
    const int wk  = (bid & 7) * NBLK + (bid >> 3);
    const int b   = wk / NBLK;
    const int P0  = (wk % NBLK) * BNP;

    const int tid  = threadIdx.x;
    const int lane = tid & 63;
    const int wid  = __builtin_amdgcn_readfirstlane(tid >> 6);
    const int l15  = lane & 15;
    const int lhi  = lane >> 4;

    const ushort* vrow = v + (size_t)(b * PIMG + P0) * KCH;
    const int abase = (wid * 32 + l15) * KCH + lhi * 8;

    f32x4 acc[2][4] = {};

    auto stage = [&](int ck, ushort* buf) {
        #pragma unroll
        for (int u = 0; u < 3; ++u) {
            const int flat = u * 512 + tid;      // 1536 x 16B units
            const int row  = flat / 24;          // 24 units per 384B row
            const int col  = flat - row * 24;
            const short8 val = *reinterpret_cast<const short8*>(
                vrow + (size_t)row * KCH + ck * KCB + col * 8);
            *reinterpret_cast<short8*>(buf + row * VPB + col * 8) = val;
        }
    };
    auto gemm = [&](int ck, const ushort* buf) {
        const int k0 = ck * KCB;
        #pragma unroll
        for (int kk = 0; kk < 6; ++kk) {
            short8 afr[2], bfr[4];
            #pragma unroll
            for (int mi = 0; mi < 2; ++mi)
                afr[mi] = *reinterpret_cast<const short8*>(
                    W2bf + abase + mi * 16 * KCH + k0 + kk * 32);
            #pragma unroll
            for (int ni = 0; ni < 4; ++ni)
                bfr[ni] = *reinterpret_cast<const short8*>(
                    buf + (ni * 16 + l15) * VPB + kk * 32 + lhi * 8);
            #pragma unroll
            for (int mi = 0; mi < 2; ++mi)
                #pragma unroll
                for (int ni = 0; ni < 4; ++ni)
                    acc[mi][ni] = __builtin_amdgcn_mfma_f32_16x16x32_bf16(
                        afr[mi], bfr[ni], acc[mi][ni], 0, 0, 0);
        }
    };

    stage(0, vt[0]);
    __syncthreads();
    for (int ck = 0; ck < 6; ++ck) {
        if (ck < 5) stage(ck + 1, vt[(ck + 1) & 1]);   // loads fly under MFMA
        gemm(ck, vt[ck & 1]);
        __syncthreads();
    }

    #pragma unroll
    for (int mi = 0; mi < 2; ++mi) {
        #pragma unroll
        for (int r = 0; r < 4; ++r) {
            const int oc = wid * 32 + mi * 16 + lhi * 4 + r;
            const float s2 = bn2g[oc] * rsqrtf(bn2v[oc] + 1e-5f);
            const float t2 = (cbias[oc] - bn2m[oc]) * s2 + bn2b[oc];
            float* op = out + ((size_t)(b * OCN + oc)) * PIMG + P0;
            #pragma unroll
            for (int ni = 0; ni < 4; ++ni)
                op[ni * 16 + l15] = fmaxf(fmaf(acc[mi][ni][r], s2, t2), 0.f);
        }
    }
}

// =================== fused fallback (round-5 kernel, 210us) ===================
template<bool FAST>
__global__ __launch_bounds__(NT, 4) void rfa_mfma3_kernel(
    const float* __restrict__ x,
    const float* __restrict__ w1,   const float* __restrict__ gfw,
    const float* __restrict__ bn1g, const float* __restrict__ bn1b,
    const float* __restrict__ bn1m, const float* __restrict__ bn1v,
    const float* __restrict__ W2f,
    const ushort* __restrict__ W2bf, const float* __restrict__ gws,
    const float* __restrict__ shiftv, const float* __restrict__ w1s,
    const float* __restrict__ cbias,
    const float* __restrict__ bn2g, const float* __restrict__ bn2b,
    const float* __restrict__ bn2m, const float* __restrict__ bn2v,
    float* __restrict__ out)
{
    __shared__ ushort vlds[2][BNP * VP];

    const int tid = threadIdx.x;
    const int b   = blockIdx.x / NBLK;
    const int P0  = (blockIdx.x % NBLK) * BNP;

    const int px  = tid & 63;
    const int p   = P0 + px;
    const int h   = p / WWD;
    const int w   = p - h * WWD;
    const int wid = __builtin_amdgcn_readfirstlane(tid >> 6);
    const int l15 = px & 15;
    const int lhi = px >> 4;

    int hro[3], wxc[3];
    f32x2 okp[4];
    float ok8;
    {
        float okr[3], okc[3];
        #pragma unroll
        for (int d = 0; d < 3; ++d) {
            int hy = h + d - 1;
            okr[d] = ((unsigned)hy < (unsigned)HH) ? 1.f : 0.f;
            hro[d] = ((hy < 0) ? 0 : (hy > 95 ? 95 : hy)) * WWD;
            int wx = w + d - 1;
            okc[d] = ((unsigned)wx < (unsigned)WWD) ? 1.f : 0.f;
            wxc[d] = (wx < 0) ? 0 : (wx > 95 ? 95 : wx);
        }
        okp[0] = f32x2{okr[0]*okc[0], okr[0]*okc[1]};
        okp[1] = f32x2{okr[0]*okc[2], okr[1]*okc[0]};
        okp[2] = f32x2{okr[1]*okc[1], okr[1]*okc[2]};
        okp[3] = f32x2{okr[2]*okc[0], okr[2]*okc[1]};
        ok8    = okr[2]*okc[2];
    }

    f32x4 acc[2][4] = {};
    const float* xb = x + (size_t)b * CCH * PIMG;
    const int abase = (wid * 32 + l15) * KCH + lhi * 8;

    auto chan = [&](int q) { return (q >> 2) * CC + wid * 4 + (q & 3); };
    auto load_nb2 = [&](int c) {
        const float* xc = xb + (size_t)c * PIMG;
        NB r;
        float v0 = xc[hro[0]+wxc[0]], v1 = xc[hro[0]+wxc[1]], v2 = xc[hro[0]+wxc[2]];
        float v3 = xc[hro[1]+wxc[0]], v4 = xc[hro[1]+wxc[1]], v5 = xc[hro[1]+wxc[2]];
        float v6 = xc[hro[2]+wxc[0]], v7 = xc[hro[2]+wxc[1]], v8 = xc[hro[2]+wxc[2]];
        r.p[0] = f32x2{v0,v1}; r.p[1] = f32x2{v2,v3};
        r.p[2] = f32x2{v4,v5}; r.p[3] = f32x2{v6,v7};
        r.s = v8;
        return r;
    };

    NB nb = load_nb2(chan(0));

    for (int ck = 0; ck < 4; ++ck) {
        ushort* vbuf = vlds[ck & 1];
        #pragma unroll
        for (int pass = 0; pass < 4; ++pass) {
            const int q  = ck * 4 + pass;
            const int qn = (q + 1 > 15) ? 15 : q + 1;
            NB nbn = load_nb2(chan(qn));

            const int c  = chan(q);
            const int cl = wid * 4 + pass;
            f32x2 e[4];
            #pragma unroll
            for (int i = 0; i < 4; ++i) e[i] = nb.p[i] * okp[i];
            const float e8 = nb.s * ok8;
            f32x2 ps2 = (e[0] + e[1]) + (e[2] + e[3]);
            const float psum = ps2[0] + ps2[1] + e8;

            float at[9], ss = 0.f;
            if constexpr (FAST) {
                const float* w1r = w1s + c * 12;
                #pragma unroll
                for (int n = 0; n < 9; ++n) { at[n] = __builtin_exp2f(psum * w1r[n]); ss += at[n]; }
            } else {
                const float pooled = psum * (1.f / 9.f);
                const float* w1r = w1 + c * 9;
                #pragma unroll
                for (int n = 0; n < 9; ++n) { at[n] = __expf(pooled * w1r[n]); ss += at[n]; }
            }
            const float rs = __builtin_amdgcn_rcpf(ss);

            ushort* vp = vbuf + px * VP + cl * 9;
            #pragma unroll
            for (int n = 0; n < 9; ++n) {
                const int ch = c * 9 + n;
                float f;
                if constexpr (FAST) {
                    const f32x2* gp = reinterpret_cast<const f32x2*>(gws + ch * 12);
                    f32x2 f2 = f32x2{shiftv[ch], 0.f};
                    #pragma unroll
                    for (int u4 = 0; u4 < 4; ++u4) f2 = __builtin_elementwise_fma(e[u4], gp[u4], f2);
                    f = f2[0] + f2[1];
                    f = fmaf(e8, gws[ch * 12 + 8], f);
                } else {
                    const float* gr = gfw + ch * 9;
                    float cv = 0.f;
                    cv = fmaf(e[0][0], gr[0], cv); cv = fmaf(e[0][1], gr[1], cv);
                    cv = fmaf(e[1][0], gr[2], cv); cv = fmaf(e[1][1], gr[3], cv);
                    cv = fmaf(e[2][0], gr[4], cv); cv = fmaf(e[2][1], gr[5], cv);
                    cv = fmaf(e[3][0], gr[6], cv); cv = fmaf(e[3][1], gr[7], cv);
                    cv = fmaf(e8, gr[8], cv);
                    const float sc = bn1g[ch] * rsqrtf(bn1v[ch] + 1e-5f);
                    f = (cv - bn1m[ch]) * sc + bn1b[ch];
                }
                f = fmaxf(f, 0.f) * (at[n] * rs);
                vp[n] = bf16bits(f);
            }
            nb = nbn;
        }
        __syncthreads();

        const int k0 = ck * KC;
        #pragma unroll 3
        for (int kk = 0; kk < 9; ++kk) {
            short8 afr[2], bfr[4];
            #pragma unroll
            for (int mi = 0; mi < 2; ++mi) {
                const int ai = abase + mi * 16 * KCH + k0 + kk * 32;
                if constexpr (FAST) {
                    afr[mi] = *reinterpret_cast<const short8*>(W2bf + ai);
                } else {
                    const f32x4 f0 = *reinterpret_cast<const f32x4*>(W2f + ai);
                    const f32x4 f1 = *reinterpret_cast<const f32x4*>(W2f + ai + 4);
                    short8 a;
                    a[0]=(short)bf16bits(f0[0]); a[1]=(short)bf16bits(f0[1]);
                    a[2]=(short)bf16bits(f0[2]); a[3]=(short)bf16bits(f0[3]);
                    a[4]=(short)bf16bits(f1[0]); a[5]=(short)bf16bits(f1[1]);
                    a[6]=(short)bf16bits(f1[2]); a[7]=(short)bf16bits(f1[3]);
                    afr[mi] = a;
                }
            }
            #pragma unroll
            for (int ni = 0; ni < 4; ++ni)
                bfr[ni] = *reinterpret_cast<const short8*>(
                    vbuf + (ni * 16 + l15) * VP + kk * 32 + lhi * 8);
            #pragma unroll
            for (int mi = 0; mi < 2; ++mi)
                #pragma unroll
                for (int ni = 0; ni < 4; ++ni)
                    acc[mi][ni] = __builtin_amdgcn_mfma_f32_16x16x32_bf16(
                        afr[mi], bfr[ni], acc[mi][ni], 0, 0, 0);
        }
    }

    #pragma unroll
    for (int mi = 0; mi < 2; ++mi) {
        #pragma unroll
        for (int r = 0; r < 4; ++r) {
            const int oc = wid * 32 + mi * 16 + lhi * 4 + r;
            const float s2 = bn2g[oc] * rsqrtf(bn2v[oc] + 1e-5f);
            const float t2 = (cbias[oc] - bn2m[oc]) * s2 + bn2b[oc];
            float* op = out + ((size_t)(b * OCN + oc)) * PIMG + P0;
            #pragma unroll
            for (int ni = 0; ni < 4; ++ni)
                op[ni * 16 + l15] = fmaxf(fmaf(acc[mi][ni][r], s2, t2), 0.f);
        }
    }
}

extern "C" void kernel_launch(void* const* d_in, const int* in_sizes, int n_in,
                              void* d_out, int out_size, void* d_ws, size_t ws_size,
                              hipStream_t stream) {
    const float* xx   = (const float*)d_in[0];
    const float* w1   = (const float*)d_in[1];
    const float* gfw  = (const float*)d_in[2];
    const float* bn1g = (const float*)d_in[3];
    const float* bn1b = (const float*)d_in[4];
    const float* bn1m = (const float*)d_in[5];
    const float* bn1v = (const float*)d_in[6];
    const float* W2   = (const float*)d_in[7];
    const float* cb   = (const float*)d_in[8];
    const float* bn2g = (const float*)d_in[9];
    const float* bn2b = (const float*)d_in[10];
    const float* bn2m = (const float*)d_in[11];
    const float* bn2v = (const float*)d_in[12];
    float* o = (float*)d_out;

    const size_t v_bytes   = (size_t)8 * PIMG * KCH * sizeof(ushort);   // 169,869,312
    const size_t w2_bytes  = (size_t)OCN * KCH * sizeof(ushort);        // 589,824
    const size_t gws_bytes = (size_t)KCH * 12 * sizeof(float);
    const size_t shf_bytes = (size_t)KCH * sizeof(float);
    const size_t w1s_bytes = (size_t)CCH * 12 * sizeof(float);

    const size_t split_need = v_bytes + w2_bytes + gws_bytes + shf_bytes + w1s_bytes;
    const size_t fused_need = w2_bytes + gws_bytes + shf_bytes + w1s_bytes;

    const int ptot = OCN * KCH + KCH + CCH;
    dim3 grid(8 * NBLK);
    dim3 blk(NT);

    if (ws_size >= split_need) {
        ushort* vbuf = (ushort*)d_ws;
        ushort* W2bf = (ushort*)((char*)d_ws + v_bytes);
        float*  gwsp = (float*)((char*)d_ws + v_bytes + w2_bytes);
        float*  shf  = (float*)((char*)gwsp + gws_bytes);
        float*  w1sp = (float*)((char*)shf + shf_bytes);
        prep_kernel<<<(ptot + 255) / 256, 256, 0, stream>>>(
            W2, gfw, bn1g, bn1b, bn1m, bn1v, w1, W2bf, gwsp, shf, w1sp);
        rfa_prod_kernel<<<grid, blk, 0, stream>>>(xx, gwsp, shf, w1sp, vbuf);
        rfa_gemm_kernel<<<grid, blk, 0, stream>>>(
            W2bf, vbuf, cb, bn2g, bn2b, bn2m, bn2v, o);
    } else if (ws_size >= fused_need) {
        ushort* W2bf = (ushort*)d_ws;
        float*  gwsp = (float*)((char*)d_ws + w2_bytes);
        float*  shf  = (float*)((char*)gwsp + gws_bytes);
        float*  w1sp = (float*)((char*)shf + shf_bytes);
        prep_kernel<<<(ptot + 255) / 256, 256, 0, stream>>>(
            W2, gfw, bn1g, bn1b, bn1m, bn1v, w1, W2bf, gwsp, shf, w1sp);
        rfa_mfma3_kernel<true><<<grid, blk, 0, stream>>>(
            xx, w1, gfw, bn1g, bn1b, bn1m, bn1v, W2, W2bf, gwsp, shf, w1sp,
            cb, bn2g, bn2b, bn2m, bn2v, o);
    } else {
        rfa_mfma3_kernel<false><<<grid, blk, 0, stream>>>(
            xx, w1, gfw, bn1g, bn1b, bn1m, bn1v, W2, nullptr, nullptr, nullptr, nullptr,
            cb, bn2g, bn2b, bn2m, bn2v, o);
    }
}

// Round 12
// 216.182 us; speedup vs baseline: 2.0630x; 2.0630x over previous
//
#include <hip/hip_runtime.h>
#include <hip/hip_bf16.h>

// RFAConv fused MFMA, round 12: r5 lockstep base (210us) +
//  (1) XCD swizzle ISOLATED (r8 proved FETCH 94->37MB; no prefetch queue this time),
//  (2) fully-unrolled pass loop with distance-2 register tap prefetch ->
//      two independent produce streams in scheduler scope at all times (ILP covers
//      L2-hit latency; TLP is capped at 4 waves/SIMD by LDS).
// VGPR budget free up to 128 (2 blocks/CU is LDS-capped).

#define CCH  128
#define OCN  256
#define HH   96
#define WWD  96
#define KCH  1152
#define PIMG 9216
#define BNP  64       // pixels per block
#define NBLK 144
#define CC   32       // channels per chunk
#define KC   288
#define VP   296      // LDS row pitch (shorts), rows 16B-aligned
#define NT   512

using short8   = __attribute__((ext_vector_type(8))) short;
using f32x4    = __attribute__((ext_vector_type(4))) float;
using f32x2    = __attribute__((ext_vector_type(2))) float;
using ushort2v = __attribute__((ext_vector_type(2))) ushort;

__device__ __forceinline__ ushort bf16bits(float f) {
    __hip_bfloat16 h = __float2bfloat16(f);
    return *reinterpret_cast<ushort*>(&h);
}

struct NB { f32x2 p[4]; float s; };

// ---- prepass: W2->bf16, fold bn1 into dwconv weights, w1*(1/9)*log2e ----
__global__ void prep_kernel(const float* __restrict__ W2, const float* __restrict__ gfw,
                            const float* __restrict__ bn1g, const float* __restrict__ bn1b,
                            const float* __restrict__ bn1m, const float* __restrict__ bn1v,
                            const float* __restrict__ w1,
                            ushort* __restrict__ W2bf, float* __restrict__ gws,
                            float* __restrict__ shiftv, float* __restrict__ w1s) {
    int i = blockIdx.x * 256 + threadIdx.x;
    if (i < OCN * KCH) {
        W2bf[i] = bf16bits(W2[i]);
    } else if (i < OCN * KCH + KCH) {
        const int ch = i - OCN * KCH;
        const float sc = bn1g[ch] * rsqrtf(bn1v[ch] + 1e-5f);
        shiftv[ch] = bn1b[ch] - bn1m[ch] * sc;
        #pragma unroll
        for (int t = 0; t < 9; ++t) gws[ch * 12 + t] = gfw[ch * 9 + t] * sc;
    } else if (i < OCN * KCH + KCH + CCH) {
        const int c = i - OCN * KCH - KCH;
        #pragma unroll
        for (int n = 0; n < 9; ++n)
            w1s[c * 12 + n] = w1[c * 9 + n] * (1.f / 9.f) * 1.4426950408889634f;
    }
}

template<bool FAST>
__global__ __launch_bounds__(NT, 4) void rfa_r12_kernel(
    const float* __restrict__ x,
    const float* __restrict__ w1,   const float* __restrict__ gfw,
    const float* __restrict__ bn1g, const float* __restrict__ bn1b,
    const float* __restrict__ bn1m, const float* __restrict__ bn1v,
    const float* __restrict__ W2f,
    const ushort* __restrict__ W2bf, const float* __restrict__ gws,
    const float* __restrict__ shiftv, const float* __restrict__ w1s,
    const float* __restrict__ cbias,
    const float* __restrict__ bn2g, const float* __restrict__ bn2b,
    const float* __restrict__ bn2m, const float* __restrict__ bn2v,
    float* __restrict__ out)
{
    __shared__ ushort vlds[2][BNP * VP];   // 75776 B -> 2 blocks/CU

    // XCD swizzle: 1152 blocks, block i -> XCD i%8; bid&7 selects image -> each
    // XCD works one image (x slice 4.7MB + W2bf 0.6MB ~ L2). Bijective.
    const int bid = blockIdx.x;
    const int b   = bid & 7;
    const int P0  = (bid >> 3) * BNP;

    const int tid = threadIdx.x;
    const int px  = tid & 63;
    const int p   = P0 + px;
    const int h   = p / WWD;
    const int w   = p - h * WWD;
    const int wid = __builtin_amdgcn_readfirstlane(tid >> 6);
    const int l15 = px & 15;
    const int lhi = px >> 4;

    // ---- boundary precompute ----
    int off9[9];
    f32x2 okp[4];
    float ok8;
    {
        float okr[3], okc[3];
        int hro[3], wxc[3];
        #pragma unroll
        for (int d = 0; d < 3; ++d) {
            int hy = h + d - 1;
            okr[d] = ((unsigned)hy < (unsigned)HH) ? 1.f : 0.f;
            hro[d] = ((hy < 0) ? 0 : (hy > 95 ? 95 : hy)) * WWD;
            int wx = w + d - 1;
            okc[d] = ((unsigned)wx < (unsigned)WWD) ? 1.f : 0.f;
            wxc[d] = (wx < 0) ? 0 : (wx > 95 ? 95 : wx);
        }
        #pragma unroll
        for (int dy = 0; dy < 3; ++dy)
            #pragma unroll
            for (int dx = 0; dx < 3; ++dx) off9[dy*3+dx] = hro[dy] + wxc[dx];
        okp[0] = f32x2{okr[0]*okc[0], okr[0]*okc[1]};
        okp[1] = f32x2{okr[0]*okc[2], okr[1]*okc[0]};
        okp[2] = f32x2{okr[1]*okc[1], okr[1]*okc[2]};
        okp[3] = f32x2{okr[2]*okc[0], okr[2]*okc[1]};
        ok8    = okr[2]*okc[2];
    }

    f32x4 acc[2][4] = {};
    const float* xb = x + (size_t)b * CCH * PIMG;
    const int abase = (wid * 32 + l15) * KCH + lhi * 8;

    auto chan = [&](int q) { return (q >> 2) * CC + wid * 4 + (q & 3); };
    auto load_nb = [&](int c) {
        const float* xc = xb + (size_t)c * PIMG;
        NB r;
        float v0 = xc[off9[0]], v1 = xc[off9[1]], v2 = xc[off9[2]];
        float v3 = xc[off9[3]], v4 = xc[off9[4]], v5 = xc[off9[5]];
        float v6 = xc[off9[6]], v7 = xc[off9[7]], v8 = xc[off9[8]];
        r.p[0] = f32x2{v0,v1}; r.p[1] = f32x2{v2,v3};
        r.p[2] = f32x2{v4,v5}; r.p[3] = f32x2{v6,v7};
        r.s = v8;
        return r;
    };

    auto produce_one = [&](const NB& nb, int c, int cl, ushort* vbuf, bool evenp) {
        f32x2 e[4];
        #pragma unroll
        for (int i = 0; i < 4; ++i) e[i] = nb.p[i] * okp[i];
        const float e8 = nb.s * ok8;
        f32x2 ps2 = (e[0] + e[1]) + (e[2] + e[3]);
        const float psum = ps2[0] + ps2[1] + e8;

        float at[9], ss = 0.f;
        if constexpr (FAST) {
            const float* w1r = w1s + c * 12;     // (1/9)*log2e folded
            #pragma unroll
            for (int n = 0; n < 9; ++n) { at[n] = __builtin_exp2f(psum * w1r[n]); ss += at[n]; }
        } else {
            const float pooled = psum * (1.f / 9.f);
            const float* w1r = w1 + c * 9;
            #pragma unroll
            for (int n = 0; n < 9; ++n) { at[n] = __expf(pooled * w1r[n]); ss += at[n]; }
        }
        const float rs = __builtin_amdgcn_rcpf(ss);

        ushort u[9];
        #pragma unroll
        for (int n = 0; n < 9; ++n) {
            const int ch = c * 9 + n;
            float f;
            if constexpr (FAST) {
                const f32x2* gp = reinterpret_cast<const f32x2*>(gws + ch * 12);
                f32x2 f2 = f32x2{shiftv[ch], 0.f};
                #pragma unroll
                for (int u4 = 0; u4 < 4; ++u4) f2 = __builtin_elementwise_fma(e[u4], gp[u4], f2);
                f = f2[0] + f2[1];
                f = fmaf(e8, gws[ch * 12 + 8], f);
            } else {
                const float* gr = gfw + ch * 9;
                float cv = 0.f;
                cv = fmaf(e[0][0], gr[0], cv); cv = fmaf(e[0][1], gr[1], cv);
                cv = fmaf(e[1][0], gr[2], cv); cv = fmaf(e[1][1], gr[3], cv);
                cv = fmaf(e[2][0], gr[4], cv); cv = fmaf(e[2][1], gr[5], cv);
                cv = fmaf(e[3][0], gr[6], cv); cv = fmaf(e[3][1], gr[7], cv);
                cv = fmaf(e8, gr[8], cv);
                const float sc = bn1g[ch] * rsqrtf(bn1v[ch] + 1e-5f);
                f = (cv - bn1m[ch]) * sc + bn1b[ch];
            }
            f = fmaxf(f, 0.f) * (at[n] * rs);
            u[n] = bf16bits(f);
        }
        ushort* vp = vbuf + px * VP + cl * 9;
        if (evenp) {
            ushort2v* q2 = reinterpret_cast<ushort2v*>(vp);
            q2[0] = ushort2v{u[0], u[1]}; q2[1] = ushort2v{u[2], u[3]};
            q2[2] = ushort2v{u[4], u[5]}; q2[3] = ushort2v{u[6], u[7]};
            vp[8] = u[8];
        } else {
            vp[0] = u[0];
            ushort2v* q2 = reinterpret_cast<ushort2v*>(vp + 1);
            q2[0] = ushort2v{u[1], u[2]}; q2[1] = ushort2v{u[3], u[4]};
            q2[2] = ushort2v{u[5], u[6]}; q2[3] = ushort2v{u[7], u[8]};
        }
    };

    // distance-2 register prefetch; passes fully unrolled inside each chunk so the
    // scheduler always sees two independent produce streams.
    NB nb0 = load_nb(chan(0));
    NB nb1 = load_nb(chan(1));

    for (int ck = 0; ck < 4; ++ck) {
        ushort* vbuf = vlds[ck & 1];

        #pragma unroll
        for (int pass = 0; pass < 4; ++pass) {
            const int q  = ck * 4 + pass;
            const int qn = (q + 2 > 15) ? 15 : q + 2;
            NB nbn = load_nb(chan(qn));          // taps 2 passes ahead
            produce_one(nb0, chan(q), wid * 4 + pass, vbuf, (pass & 1) == 0);
            nb0 = nb1;
            nb1 = nbn;
        }
        __syncthreads();   // vbuf(ck) ready; other buffer's GEMM complete

        // ---------- GEMM chunk ck: 9 ksteps of 32 ----------
        const int k0 = ck * KC;
        #pragma unroll 3
        for (int kk = 0; kk < 9; ++kk) {
            short8 afr[2], bfr[4];
            #pragma unroll
            for (int mi = 0; mi < 2; ++mi) {
                const int ai = abase + mi * 16 * KCH + k0 + kk * 32;
                if constexpr (FAST) {
                    afr[mi] = *reinterpret_cast<const short8*>(W2bf + ai);
                } else {
                    const f32x4 f0 = *reinterpret_cast<const f32x4*>(W2f + ai);
                    const f32x4 f1 = *reinterpret_cast<const f32x4*>(W2f + ai + 4);
                    short8 a;
                    a[0]=(short)bf16bits(f0[0]); a[1]=(short)bf16bits(f0[1]);
                    a[2]=(short)bf16bits(f0[2]); a[3]=(short)bf16bits(f0[3]);
                    a[4]=(short)bf16bits(f1[0]); a[5]=(short)bf16bits(f1[1]);
                    a[6]=(short)bf16bits(f1[2]); a[7]=(short)bf16bits(f1[3]);
                    afr[mi] = a;
                }
            }
            #pragma unroll
            for (int ni = 0; ni < 4; ++ni)
                bfr[ni] = *reinterpret_cast<const short8*>(
                    vbuf + (ni * 16 + l15) * VP + kk * 32 + lhi * 8);
            #pragma unroll
            for (int mi = 0; mi < 2; ++mi)
                #pragma unroll
                for (int ni = 0; ni < 4; ++ni)
                    acc[mi][ni] = __builtin_amdgcn_mfma_f32_16x16x32_bf16(
                        afr[mi], bfr[ni], acc[mi][ni], 0, 0, 0);
        }
    }

    // ---------- epilogue: bn2 + relu ----------
    #pragma unroll
    for (int mi = 0; mi < 2; ++mi) {
        #pragma unroll
        for (int r = 0; r < 4; ++r) {
            const int oc = wid * 32 + mi * 16 + lhi * 4 + r;
            const float s2 = bn2g[oc] * rsqrtf(bn2v[oc] + 1e-5f);
            const float t2 = (cbias[oc] - bn2m[oc]) * s2 + bn2b[oc];
            float* op = out + ((size_t)(b * OCN + oc)) * PIMG + P0;
            #pragma unroll
            for (int ni = 0; ni < 4; ++ni)
                op[ni * 16 + l15] = fmaxf(fmaf(acc[mi][ni][r], s2, t2), 0.f);
        }
    }
}

extern "C" void kernel_launch(void* const* d_in, const int* in_sizes, int n_in,
                              void* d_out, int out_size, void* d_ws, size_t ws_size,
                              hipStream_t stream) {
    const float* xx   = (const float*)d_in[0];
    const float* w1   = (const float*)d_in[1];
    const float* gfw  = (const float*)d_in[2];
    const float* bn1g = (const float*)d_in[3];
    const float* bn1b = (const float*)d_in[4];
    const float* bn1m = (const float*)d_in[5];
    const float* bn1v = (const float*)d_in[6];
    const float* W2   = (const float*)d_in[7];
    const float* cb   = (const float*)d_in[8];
    const float* bn2g = (const float*)d_in[9];
    const float* bn2b = (const float*)d_in[10];
    const float* bn2m = (const float*)d_in[11];
    const float* bn2v = (const float*)d_in[12];
    float* o = (float*)d_out;

    const size_t off_gws   = (size_t)OCN * KCH * sizeof(ushort);
    const size_t off_shift = off_gws + (size_t)KCH * 12 * sizeof(float);
    const size_t off_w1s   = off_shift + (size_t)KCH * sizeof(float);
    const size_t ws_need   = off_w1s + (size_t)CCH * 12 * sizeof(float);

    dim3 grid(8 * NBLK);
    dim3 blk(NT);

    if (ws_size >= ws_need) {
        ushort* W2bf = (ushort*)d_ws;
        float*  gwsp = (float*)((char*)d_ws + off_gws);
        float*  shf  = (float*)((char*)d_ws + off_shift);
        float*  w1sp = (float*)((char*)d_ws + off_w1s);
        const int ptot = OCN * KCH + KCH + CCH;
        prep_kernel<<<(ptot + 255) / 256, 256, 0, stream>>>(
            W2, gfw, bn1g, bn1b, bn1m, bn1v, w1, W2bf, gwsp, shf, w1sp);
        rfa_r12_kernel<true><<<grid, blk, 0, stream>>>(
            xx, w1, gfw, bn1g, bn1b, bn1m, bn1v, W2, W2bf, gwsp, shf, w1sp,
            cb, bn2g, bn2b, bn2m, bn2v, o);
    } else {
        rfa_r12_kernel<false><<<grid, blk, 0, stream>>>(
            xx, w1, gfw, bn1g, bn1b, bn1m, bn1v, W2, nullptr, nullptr, nullptr, nullptr,
            cb, bn2g, bn2b, bn2m, bn2v, o);
    }
}